// Round 1
// baseline (670.483 us; speedup 1.0000x reference)
//
#include <hip/hip_runtime.h>

#define L_TOT 65536
#define CCH 64
#define MD 128

// ws layout (float offsets)
#define WS_UG   0        // [4][128][8]
#define WS_VG   4096     // [4][128][8]
#define WS_A    8192     // [4][128]
#define WS_GB1  8704     // [4][128]
#define WS_CG   9216     // [4][64][128]
#define WS_XS   65536    // [4][65536][128]  (~134 MB)

__global__ __launch_bounds__(128) void mod_kernel(
    const float* __restrict__ g,
    const float* __restrict__ U_base, const float* __restrict__ V_base,
    const float* __restrict__ a_base, const float* __restrict__ out_proj_w,
    const float* __restrict__ mod_uv_w, const float* __restrict__ mod_uv_b,
    const float* __restrict__ mod_a_w, const float* __restrict__ mod_a_b,
    const float* __restrict__ mod_B_w, const float* __restrict__ mod_B_b,
    const float* __restrict__ mod_C_w, const float* __restrict__ mod_C_b,
    float* __restrict__ ws)
{
    __shared__ float gsh[64];
    __shared__ float uvs[16];   // clipped gU (0..7), gV (8..15)
    __shared__ float gas[128];  // clipped ga
    __shared__ float gBs[128];  // 1 + clipped gB
    __shared__ float gCs[64];   // 1 + clipped gC
    const int b = blockIdx.x, tid = threadIdx.x;
    if (tid < 64) gsh[tid] = g[b * 64 + tid];
    __syncthreads();
    if (tid < 16) {
        float s = mod_uv_b[tid];
        for (int d = 0; d < 64; ++d) s += mod_uv_w[tid * 64 + d] * gsh[d];
        uvs[tid] = fminf(0.5f, fmaxf(-0.5f, s));
    }
    {
        float s = mod_a_b[tid];
        for (int d = 0; d < 64; ++d) s += mod_a_w[tid * 64 + d] * gsh[d];
        gas[tid] = fminf(2.0f, fmaxf(-2.0f, s));
    }
    {
        float s = mod_B_b[tid];
        for (int d = 0; d < 64; ++d) s += mod_B_w[tid * 64 + d] * gsh[d];
        gBs[tid] = 1.0f + fminf(1.0f, fmaxf(-1.0f, s));
    }
    if (tid < 64) {
        float s = mod_C_b[tid];
        for (int d = 0; d < 64; ++d) s += mod_C_w[tid * 64 + d] * gsh[d];
        gCs[tid] = 1.0f + fminf(0.5f, fmaxf(-0.5f, s));
    }
    __syncthreads();
    // derive per-b tensors
    for (int idx = tid; idx < 1024; idx += 128) {
        int m = idx >> 3, r = idx & 7;
        ws[WS_UG + (b * 128 + m) * 8 + r] = U_base[m * 8 + r] * (1.0f + uvs[r]);
        ws[WS_VG + (b * 128 + m) * 8 + r] = V_base[m * 8 + r] * (1.0f + uvs[8 + r]);
    }
    ws[WS_A   + b * 128 + tid] = a_base[tid] + gas[tid];
    ws[WS_GB1 + b * 128 + tid] = gBs[tid];
    for (int idx = tid; idx < 8192; idx += 128) {
        int c = idx >> 7, m = idx & 127;
        ws[WS_CG + (b * 64 + c) * 128 + m] = out_proj_w[c * 128 + m] * gCs[c];
    }
}

// x_seq[b][l][m] = (1+gB[b][m]) * (sum_c W[m][c]*x[b][c][l] + bias[m])
__global__ __launch_bounds__(256) void inproj_kernel(
    const float* __restrict__ x, const float* __restrict__ W,
    const float* __restrict__ bias, const float* __restrict__ ws,
    float* __restrict__ xs)
{
    __shared__ float xsh[64][68];    // [c][l_col], padded for float4 align
    __shared__ float Wsh[128][65];   // [m][c], padded
    const int tid = threadIdx.x;
    const int b = blockIdx.y;
    const int l0 = blockIdx.x * 64;

    for (int rep = 0; rep < 16; ++rep) {
        int idx = rep * 256 + tid;
        int c = idx >> 6, col = idx & 63;
        xsh[c][col] = x[((size_t)(b * 64 + c)) * L_TOT + l0 + col];
    }
    for (int rep = 0; rep < 32; ++rep) {
        int idx = rep * 256 + tid;
        Wsh[idx >> 6][idx & 63] = W[idx];
    }
    const int m = tid & 127, lg = tid >> 7;
    float acc[32];
    #pragma unroll
    for (int j = 0; j < 32; ++j) acc[j] = 0.0f;
    __syncthreads();

    for (int c = 0; c < 64; ++c) {
        float w = Wsh[m][c];
        #pragma unroll
        for (int j4 = 0; j4 < 8; ++j4) {
            float4 xv = *(const float4*)&xsh[c][lg * 32 + j4 * 4];
            acc[j4 * 4 + 0] += w * xv.x;
            acc[j4 * 4 + 1] += w * xv.y;
            acc[j4 * 4 + 2] += w * xv.z;
            acc[j4 * 4 + 3] += w * xv.w;
        }
    }
    const float gb1 = ws[WS_GB1 + b * 128 + m];
    const float bm = bias[m];
    #pragma unroll
    for (int j = 0; j < 32; ++j) {
        int l = l0 + lg * 32 + j;
        xs[((size_t)b * L_TOT + l) * 128 + m] = gb1 * (acc[j] + bm);
    }
}

// One block per (b, chunk). 256 threads = 4 waves.
// wave -> (mhalf = (tid>>6)&1, rgrp = tid>>7). Thread owns m = tid&127 (duplicated).
// y: thread (c = tid&63, q = tid>>6) accumulates quarter q of the 128-dot.
__global__ __launch_bounds__(256) void scan_kernel(
    const float* __restrict__ xs, const float* __restrict__ ws,
    const float* __restrict__ h0, float* __restrict__ out)
{
    __shared__ float vpart[2][2][8];   // [buf][mhalf][r]
    __shared__ float h_sh[2][128];
    __shared__ float ypart[2][4][64];  // [buf][q][c]
    __shared__ float Ybuf[64][65];     // [c][t&63], padded

    const int tid = threadIdx.x;
    const int b = blockIdx.x >> 7, k = blockIdx.x & 127;
    const size_t l0 = (size_t)k * 512;
    const int m = tid & 127;
    const int mhalf = (tid >> 6) & 1;
    const int rbase = (tid >> 7) * 4;
    const int cq = tid & 63;
    const int q = tid >> 6;
    const int lane = tid & 63;

    float Vg4[4], Ug8[8], Cg32[32];
    {
        const float* Vg = ws + WS_VG + (b * 128 + m) * 8;
        const float* Ug = ws + WS_UG + (b * 128 + m) * 8;
        #pragma unroll
        for (int j = 0; j < 4; ++j) Vg4[j] = Vg[rbase + j];
        #pragma unroll
        for (int r = 0; r < 8; ++r) Ug8[r] = Ug[r];
        const float* Cgp = ws + WS_CG + (b * 64 + cq) * 128 + q * 32;
        #pragma unroll
        for (int j = 0; j < 32; ++j) Cg32[j] = Cgp[j];
    }
    const float a_m = ws[WS_A + b * 128 + m];
    float h = h0[m];
    const float* xsp = xs + ((size_t)b * L_TOT + l0) * 128;
    float xt_cur = xsp[m];
    float xt_nxt = 0.0f;

    for (int t = 0; t <= 512; ++t) {
        const int buf = t & 1, prev = buf ^ 1;
        // ---- Phase A ----
        if (t < 511) xt_nxt = xsp[(size_t)(t + 1) * 128 + m];
        if (t < 512) {
            float p0 = Vg4[0] * h, p1 = Vg4[1] * h, p2 = Vg4[2] * h, p3 = Vg4[3] * h;
            #pragma unroll
            for (int off = 32; off >= 1; off >>= 1) {
                p0 += __shfl_xor(p0, off);
                p1 += __shfl_xor(p1, off);
                p2 += __shfl_xor(p2, off);
                p3 += __shfl_xor(p3, off);
            }
            if (lane == 0) {
                vpart[buf][mhalf][rbase + 0] = p0;
                vpart[buf][mhalf][rbase + 1] = p1;
                vpart[buf][mhalf][rbase + 2] = p2;
                vpart[buf][mhalf][rbase + 3] = p3;
            }
        }
        if (t > 0) {
            float yp = 0.0f;
            const float* hs = &h_sh[prev][q * 32];
            #pragma unroll
            for (int j4 = 0; j4 < 8; ++j4) {
                float4 hv = *(const float4*)(hs + j4 * 4);
                yp += Cg32[j4 * 4 + 0] * hv.x + Cg32[j4 * 4 + 1] * hv.y
                    + Cg32[j4 * 4 + 2] * hv.z + Cg32[j4 * 4 + 3] * hv.w;
            }
            ypart[buf][q][cq] = yp;
        }
        __syncthreads();
        // ---- Phase B ----
        if (t < 512) {
            float Av = 0.0f;
            #pragma unroll
            for (int r = 0; r < 8; ++r)
                Av += Ug8[r] * (vpart[buf][0][r] + vpart[buf][1][r]);
            float hn = Av + a_m * h + xt_cur;
            hn = fminf(10.0f, fmaxf(-10.0f, hn));
            h = hn;
            if (tid < 128) h_sh[buf][m] = h;
            xt_cur = xt_nxt;
        }
        if (t > 0 && tid < 64) {
            float yv = ypart[buf][0][lane] + ypart[buf][1][lane]
                     + ypart[buf][2][lane] + ypart[buf][3][lane];
            yv = fminf(10.0f, fmaxf(-10.0f, yv));
            Ybuf[lane][(t - 1) & 63] = yv;
        }
        __syncthreads();
        if (t > 0 && ((t - 1) & 63) == 63) {
            const int tb = (t - 1) >> 6;
            #pragma unroll
            for (int i = 0; i < 16; ++i) {
                int c = i * 4 + (tid >> 6);
                int col = tid & 63;
                out[((size_t)(b * 64 + c)) * L_TOT + l0 + tb * 64 + col] = Ybuf[c][col];
            }
            __syncthreads();
        }
    }
}

extern "C" void kernel_launch(void* const* d_in, const int* in_sizes, int n_in,
                              void* d_out, int out_size, void* d_ws, size_t ws_size,
                              hipStream_t stream) {
    const float* x          = (const float*)d_in[0];
    const float* g          = (const float*)d_in[1];
    const float* in_proj_w  = (const float*)d_in[2];
    const float* in_proj_b  = (const float*)d_in[3];
    const float* out_proj_w = (const float*)d_in[4];
    const float* U_base     = (const float*)d_in[5];
    const float* V_base     = (const float*)d_in[6];
    const float* a_base     = (const float*)d_in[7];
    const float* mod_uv_w   = (const float*)d_in[8];
    const float* mod_uv_b   = (const float*)d_in[9];
    const float* mod_a_w    = (const float*)d_in[10];
    const float* mod_a_b    = (const float*)d_in[11];
    const float* mod_B_w    = (const float*)d_in[12];
    const float* mod_B_b    = (const float*)d_in[13];
    const float* mod_C_w    = (const float*)d_in[14];
    const float* mod_C_b    = (const float*)d_in[15];
    const float* h0         = (const float*)d_in[16];
    float* out = (float*)d_out;
    float* ws  = (float*)d_ws;

    hipLaunchKernelGGL(mod_kernel, dim3(4), dim3(128), 0, stream,
                       g, U_base, V_base, a_base, out_proj_w,
                       mod_uv_w, mod_uv_b, mod_a_w, mod_a_b,
                       mod_B_w, mod_B_b, mod_C_w, mod_C_b, ws);
    hipLaunchKernelGGL(inproj_kernel, dim3(1024, 4), dim3(256), 0, stream,
                       x, in_proj_w, in_proj_b, ws, ws + WS_XS);
    hipLaunchKernelGGL(scan_kernel, dim3(512), dim3(256), 0, stream,
                       ws + WS_XS, ws, h0, out);
}

// Round 2
// 574.027 us; speedup vs baseline: 1.1680x; 1.1680x over previous
//
#include <hip/hip_runtime.h>

#define L_TOT 65536

// ws float offsets
#define WS_UG   0        // [4][128][8]
#define WS_VG   4096     // [4][128][8]
#define WS_A    8192     // [4][128]
#define WS_GB1  8704     // [4][128]
#define WS_CGP  32768    // uint[4][64][64]: packed bf16 pairs of Cg (64 KB)
#define WS_XS   65536    // [4][65536][128] fp32 x_seq

typedef __attribute__((ext_vector_type(8))) short short8;
typedef __attribute__((ext_vector_type(4))) float f32x4;

__device__ __forceinline__ unsigned bf16rne(float f) {
    unsigned u = __builtin_bit_cast(unsigned, f);
    return (u + 0x7fffu + ((u >> 16) & 1u)) >> 16;
}

__global__ __launch_bounds__(128) void mod_kernel(
    const float* __restrict__ g,
    const float* __restrict__ U_base, const float* __restrict__ V_base,
    const float* __restrict__ a_base, const float* __restrict__ out_proj_w,
    const float* __restrict__ mod_uv_w, const float* __restrict__ mod_uv_b,
    const float* __restrict__ mod_a_w, const float* __restrict__ mod_a_b,
    const float* __restrict__ mod_B_w, const float* __restrict__ mod_B_b,
    const float* __restrict__ mod_C_w, const float* __restrict__ mod_C_b,
    float* __restrict__ ws)
{
    __shared__ float gsh[64];
    __shared__ float uvs[16];
    __shared__ float gCs[64];
    const int b = blockIdx.x, tid = threadIdx.x;
    if (tid < 64) gsh[tid] = g[b * 64 + tid];
    __syncthreads();
    if (tid < 16) {
        float s = mod_uv_b[tid];
        for (int d = 0; d < 64; ++d) s += mod_uv_w[tid * 64 + d] * gsh[d];
        uvs[tid] = fminf(0.5f, fmaxf(-0.5f, s));
    }
    float ga_v, gB_v;
    {
        float s = mod_a_b[tid];
        for (int d = 0; d < 64; ++d) s += mod_a_w[tid * 64 + d] * gsh[d];
        ga_v = fminf(2.0f, fmaxf(-2.0f, s));
    }
    {
        float s = mod_B_b[tid];
        for (int d = 0; d < 64; ++d) s += mod_B_w[tid * 64 + d] * gsh[d];
        gB_v = 1.0f + fminf(1.0f, fmaxf(-1.0f, s));
    }
    if (tid < 64) {
        float s = mod_C_b[tid];
        for (int d = 0; d < 64; ++d) s += mod_C_w[tid * 64 + d] * gsh[d];
        gCs[tid] = 1.0f + fminf(0.5f, fmaxf(-0.5f, s));
    }
    __syncthreads();
    for (int idx = tid; idx < 1024; idx += 128) {
        int m = idx >> 3, r = idx & 7;
        ws[WS_UG + (b * 128 + m) * 8 + r] = U_base[m * 8 + r] * (1.0f + uvs[r]);
        ws[WS_VG + (b * 128 + m) * 8 + r] = V_base[m * 8 + r] * (1.0f + uvs[8 + r]);
    }
    ws[WS_A   + b * 128 + tid] = a_base[tid] + ga_v;
    ws[WS_GB1 + b * 128 + tid] = gB_v;
    unsigned* CgP = (unsigned*)(ws + WS_CGP);
    for (int idx = tid; idx < 4096; idx += 128) {
        int c = idx >> 6, j = idx & 63;
        float s = gCs[c];
        float c0 = out_proj_w[c * 128 + 2 * j]     * s;
        float c1 = out_proj_w[c * 128 + 2 * j + 1] * s;
        CgP[(b * 64 + c) * 64 + j] = bf16rne(c0) | (bf16rne(c1) << 16);
    }
}

// x_seq[b][l][m] = (1+gB[b][m]) * (sum_c W[m][c]*x[b][c][l] + bias[m])
__global__ __launch_bounds__(256) void inproj_kernel(
    const float* __restrict__ x, const float* __restrict__ W,
    const float* __restrict__ bias, const float* __restrict__ ws,
    float* __restrict__ xs)
{
    __shared__ float xsh[64][68];
    __shared__ float Wsh[128][65];
    const int tid = threadIdx.x;
    const int b = blockIdx.y;
    const int l0 = blockIdx.x * 64;

    for (int rep = 0; rep < 16; ++rep) {
        int idx = rep * 256 + tid;
        int c = idx >> 6, col = idx & 63;
        xsh[c][col] = x[((size_t)(b * 64 + c)) * L_TOT + l0 + col];
    }
    for (int rep = 0; rep < 32; ++rep) {
        int idx = rep * 256 + tid;
        Wsh[idx >> 6][idx & 63] = W[idx];
    }
    const int m = tid & 127, lg = tid >> 7;
    float acc[32];
    #pragma unroll
    for (int j = 0; j < 32; ++j) acc[j] = 0.0f;
    __syncthreads();

    for (int c = 0; c < 64; ++c) {
        float w = Wsh[m][c];
        #pragma unroll
        for (int j4 = 0; j4 < 8; ++j4) {
            float4 xv = *(const float4*)&xsh[c][lg * 32 + j4 * 4];
            acc[j4 * 4 + 0] += w * xv.x;
            acc[j4 * 4 + 1] += w * xv.y;
            acc[j4 * 4 + 2] += w * xv.z;
            acc[j4 * 4 + 3] += w * xv.w;
        }
    }
    const float gb1 = ws[WS_GB1 + b * 128 + m];
    const float bm = bias[m];
    #pragma unroll
    for (int j = 0; j < 32; ++j) {
        int l = l0 + lg * 32 + j;
        xs[((size_t)b * L_TOT + l) * 128 + m] = gb1 * (acc[j] + bm);
    }
}

// One WAVE per (b, chunk): 512 blocks x 64 threads, zero barriers.
// Lane owns m0=2*lane, m1=2*lane+1. Rank-8 all-reduce via DPP + 2 shfl levels.
// Every 16 steps: y = clip(Cg * H16) via 16x16x32 bf16 MFMA, stored directly.
__global__ __launch_bounds__(64) void scan_kernel(
    const float* __restrict__ xs, const float* __restrict__ ws,
    const unsigned* __restrict__ CgP, const float* __restrict__ h0,
    float* __restrict__ out)
{
    __shared__ __align__(16) unsigned Hs[16 * 68];   // row t&15, 68-uint stride
    const int lane = threadIdx.x;
    const int bb = blockIdx.x >> 7, k = blockIdx.x & 127;
    const int m0 = 2 * lane;

    float Vg0[8], Vg1[8], Ug0[8], Ug1[8];
    {
        const float* vg = ws + WS_VG + (bb * 128 + m0) * 8;
        const float* ug = ws + WS_UG + (bb * 128 + m0) * 8;
        #pragma unroll
        for (int r = 0; r < 8; ++r) {
            Vg0[r] = vg[r]; Vg1[r] = vg[8 + r];
            Ug0[r] = ug[r]; Ug1[r] = ug[8 + r];
        }
    }
    const float a0 = ws[WS_A + bb * 128 + m0];
    const float a1 = ws[WS_A + bb * 128 + m0 + 1];
    float ha = h0[m0], hb = h0[m0 + 1];

    // Cg A-fragments: Af[ct][kc], lane -> row (lane&15) of c-tile ct, k chunk kc
    short8 Af[4][4];
    {
        const int row16 = lane & 15, grp = lane >> 4;
        #pragma unroll
        for (int ct = 0; ct < 4; ++ct)
            #pragma unroll
            for (int kc = 0; kc < 4; ++kc) {
                const unsigned* p = CgP + (bb * 64 + ct * 16 + row16) * 64 + kc * 16 + grp * 4;
                Af[ct][kc] = __builtin_bit_cast(short8, *(const uint4*)p);
            }
    }

    const float* xsp = xs + ((size_t)bb * L_TOT + (size_t)k * 512) * 128;
    float2 xf0 = *(const float2*)(xsp + 0 * 128 + m0);
    float2 xf1 = *(const float2*)(xsp + 1 * 128 + m0);
    float2 xf2 = *(const float2*)(xsp + 2 * 128 + m0);
    float2 xf3 = *(const float2*)(xsp + 3 * 128 + m0);

    float* ob[4];
    {
        int c0 = (lane >> 4) * 4;
        #pragma unroll
        for (int ct = 0; ct < 4; ++ct)
            ob[ct] = out + (size_t)(bb * 64 + ct * 16 + c0) * L_TOT + k * 512 + (lane & 15);
    }

    for (int t16 = 0; t16 < 32; ++t16) {
        #pragma unroll
        for (int i = 0; i < 16; ++i) {
            const int t = t16 * 16 + i;
            float2 xv;
            if ((i & 3) == 0) xv = xf0; else if ((i & 3) == 1) xv = xf1;
            else if ((i & 3) == 2) xv = xf2; else xv = xf3;
            // prefetch t+4 (wrap to stay in-bounds; wrapped values never used)
            {
                int tp = (t + 4) & 511;
                float2 nf = *(const float2*)(xsp + (size_t)tp * 128 + m0);
                if ((i & 3) == 0) xf0 = nf; else if ((i & 3) == 1) xf1 = nf;
                else if ((i & 3) == 2) xf2 = nf; else xf3 = nf;
            }
            // rank-8 partials over this lane's two m's
            float pr[8];
            #pragma unroll
            for (int r = 0; r < 8; ++r) pr[r] = fmaf(Vg1[r], hb, Vg0[r] * ha);
            // all-reduce across 64 lanes: DPP xor1, xor2, xor7, xor15; shfl 16, 32
            #pragma unroll
            for (int r = 0; r < 8; ++r)
                pr[r] += __builtin_bit_cast(float, __builtin_amdgcn_update_dpp(
                    0, __builtin_bit_cast(int, pr[r]), 0xB1, 0xF, 0xF, true));
            #pragma unroll
            for (int r = 0; r < 8; ++r)
                pr[r] += __builtin_bit_cast(float, __builtin_amdgcn_update_dpp(
                    0, __builtin_bit_cast(int, pr[r]), 0x4E, 0xF, 0xF, true));
            #pragma unroll
            for (int r = 0; r < 8; ++r)
                pr[r] += __builtin_bit_cast(float, __builtin_amdgcn_update_dpp(
                    0, __builtin_bit_cast(int, pr[r]), 0x141, 0xF, 0xF, true));
            #pragma unroll
            for (int r = 0; r < 8; ++r)
                pr[r] += __builtin_bit_cast(float, __builtin_amdgcn_update_dpp(
                    0, __builtin_bit_cast(int, pr[r]), 0x140, 0xF, 0xF, true));
            #pragma unroll
            for (int r = 0; r < 8; ++r) pr[r] += __shfl_xor(pr[r], 16);
            #pragma unroll
            for (int r = 0; r < 8; ++r) pr[r] += __shfl_xor(pr[r], 32);
            // Av and state update
            float av0 = pr[0] * Ug0[0];
            float av1 = pr[0] * Ug1[0];
            #pragma unroll
            for (int r = 1; r < 8; ++r) {
                av0 = fmaf(pr[r], Ug0[r], av0);
                av1 = fmaf(pr[r], Ug1[r], av1);
            }
            ha = fminf(10.0f, fmaxf(-10.0f, fmaf(a0, ha, av0) + xv.x));
            hb = fminf(10.0f, fmaxf(-10.0f, fmaf(a1, hb, av1) + xv.y));
            Hs[i * 68 + lane] = bf16rne(ha) | (bf16rne(hb) << 16);
        }
        // ---- y burst: D(64c x 16t) = Cg(64x128) * H(128x16), bf16 MFMA ----
        {
            const int row = lane & 15, grp = lane >> 4;
            short8 Bf[4];
            #pragma unroll
            for (int kc = 0; kc < 4; ++kc)
                Bf[kc] = __builtin_bit_cast(short8,
                    *(const uint4*)&Hs[row * 68 + kc * 16 + grp * 4]);
            #pragma unroll
            for (int ct = 0; ct < 4; ++ct) {
                f32x4 acc = {0.0f, 0.0f, 0.0f, 0.0f};
                #pragma unroll
                for (int kc = 0; kc < 4; ++kc)
                    acc = __builtin_amdgcn_mfma_f32_16x16x32_bf16(Af[ct][kc], Bf[kc], acc, 0, 0, 0);
                #pragma unroll
                for (int r = 0; r < 4; ++r) {
                    float y = fminf(10.0f, fmaxf(-10.0f, acc[r]));
                    ob[ct][(size_t)r * L_TOT + t16 * 16] = y;
                }
            }
        }
    }
}

extern "C" void kernel_launch(void* const* d_in, const int* in_sizes, int n_in,
                              void* d_out, int out_size, void* d_ws, size_t ws_size,
                              hipStream_t stream) {
    const float* x          = (const float*)d_in[0];
    const float* g          = (const float*)d_in[1];
    const float* in_proj_w  = (const float*)d_in[2];
    const float* in_proj_b  = (const float*)d_in[3];
    const float* out_proj_w = (const float*)d_in[4];
    const float* U_base     = (const float*)d_in[5];
    const float* V_base     = (const float*)d_in[6];
    const float* a_base     = (const float*)d_in[7];
    const float* mod_uv_w   = (const float*)d_in[8];
    const float* mod_uv_b   = (const float*)d_in[9];
    const float* mod_a_w    = (const float*)d_in[10];
    const float* mod_a_b    = (const float*)d_in[11];
    const float* mod_B_w    = (const float*)d_in[12];
    const float* mod_B_b    = (const float*)d_in[13];
    const float* mod_C_w    = (const float*)d_in[14];
    const float* mod_C_b    = (const float*)d_in[15];
    const float* h0         = (const float*)d_in[16];
    float* out = (float*)d_out;
    float* ws  = (float*)d_ws;

    hipLaunchKernelGGL(mod_kernel, dim3(4), dim3(128), 0, stream,
                       g, U_base, V_base, a_base, out_proj_w,
                       mod_uv_w, mod_uv_b, mod_a_w, mod_a_b,
                       mod_B_w, mod_B_b, mod_C_w, mod_C_b, ws);
    hipLaunchKernelGGL(inproj_kernel, dim3(1024, 4), dim3(256), 0, stream,
                       x, in_proj_w, in_proj_b, ws, ws + WS_XS);
    hipLaunchKernelGGL(scan_kernel, dim3(512), dim3(64), 0, stream,
                       ws + WS_XS, ws, (const unsigned*)(ws + WS_CGP), h0, out);
}

// Round 4
// 297.990 us; speedup vs baseline: 2.2500x; 1.9263x over previous
//
#include <hip/hip_runtime.h>

#define L_TOT 65536

// ws float offsets
#define WS_UG   0        // [4][128][8]
#define WS_VG   4096     // [4][128][8]
#define WS_A    8192     // [4][128]
#define WS_GB1  8704     // [4][128]
#define WS_CGP  32768    // uint[4][64][64]: packed bf16 pairs of Cg
#define WS_XS   65536    // [4][65536][128] fp32 x_seq

typedef __attribute__((ext_vector_type(8))) short short8;
typedef __attribute__((ext_vector_type(4))) float f32x4;

__device__ __forceinline__ unsigned bf16rne(float f) {
    unsigned u = __builtin_bit_cast(unsigned, f);
    return (u + 0x7fffu + ((u >> 16) & 1u)) >> 16;
}

// v += dpp_perm(v); all-VALU. ctrl/row_mask must be compile-time constants.
template <int CTRL, int ROW_MASK, bool BOUND>
__device__ __forceinline__ float dpp_add(float v) {
    int t = __builtin_amdgcn_update_dpp(0, __builtin_bit_cast(int, v),
                                        CTRL, ROW_MASK, 0xF, BOUND);
    return v + __builtin_bit_cast(float, t);
}

__global__ __launch_bounds__(128) void mod_kernel(
    const float* __restrict__ g,
    const float* __restrict__ U_base, const float* __restrict__ V_base,
    const float* __restrict__ a_base, const float* __restrict__ out_proj_w,
    const float* __restrict__ mod_uv_w, const float* __restrict__ mod_uv_b,
    const float* __restrict__ mod_a_w, const float* __restrict__ mod_a_b,
    const float* __restrict__ mod_B_w, const float* __restrict__ mod_B_b,
    const float* __restrict__ mod_C_w, const float* __restrict__ mod_C_b,
    float* __restrict__ ws)
{
    __shared__ float gsh[64];
    __shared__ float uvs[16];
    __shared__ float gCs[64];
    const int b = blockIdx.x, tid = threadIdx.x;
    if (tid < 64) gsh[tid] = g[b * 64 + tid];
    __syncthreads();
    if (tid < 16) {
        float s = mod_uv_b[tid];
        for (int d = 0; d < 64; ++d) s += mod_uv_w[tid * 64 + d] * gsh[d];
        uvs[tid] = fminf(0.5f, fmaxf(-0.5f, s));
    }
    float ga_v, gB_v;
    {
        float s = mod_a_b[tid];
        for (int d = 0; d < 64; ++d) s += mod_a_w[tid * 64 + d] * gsh[d];
        ga_v = fminf(2.0f, fmaxf(-2.0f, s));
    }
    {
        float s = mod_B_b[tid];
        for (int d = 0; d < 64; ++d) s += mod_B_w[tid * 64 + d] * gsh[d];
        gB_v = 1.0f + fminf(1.0f, fmaxf(-1.0f, s));
    }
    if (tid < 64) {
        float s = mod_C_b[tid];
        for (int d = 0; d < 64; ++d) s += mod_C_w[tid * 64 + d] * gsh[d];
        gCs[tid] = 1.0f + fminf(0.5f, fmaxf(-0.5f, s));
    }
    __syncthreads();
    for (int idx = tid; idx < 1024; idx += 128) {
        int m = idx >> 3, r = idx & 7;
        ws[WS_UG + (b * 128 + m) * 8 + r] = U_base[m * 8 + r] * (1.0f + uvs[r]);
        ws[WS_VG + (b * 128 + m) * 8 + r] = V_base[m * 8 + r] * (1.0f + uvs[8 + r]);
    }
    ws[WS_A   + b * 128 + tid] = a_base[tid] + ga_v;
    ws[WS_GB1 + b * 128 + tid] = gB_v;
    unsigned* CgP = (unsigned*)(ws + WS_CGP);
    for (int idx = tid; idx < 4096; idx += 128) {
        int c = idx >> 6, j = idx & 63;
        float s = gCs[c];
        float c0 = out_proj_w[c * 128 + 2 * j]     * s;
        float c1 = out_proj_w[c * 128 + 2 * j + 1] * s;
        CgP[(b * 64 + c) * 64 + j] = bf16rne(c0) | (bf16rne(c1) << 16);
    }
}

__global__ __launch_bounds__(256) void inproj_kernel(
    const float* __restrict__ x, const float* __restrict__ W,
    const float* __restrict__ bias, const float* __restrict__ ws,
    float* __restrict__ xs)
{
    __shared__ float xsh[64][68];
    __shared__ float Wsh[128][65];
    const int tid = threadIdx.x;
    const int b = blockIdx.y;
    const int l0 = blockIdx.x * 64;

    for (int rep = 0; rep < 16; ++rep) {
        int idx = rep * 256 + tid;
        int c = idx >> 6, col = idx & 63;
        xsh[c][col] = x[((size_t)(b * 64 + c)) * L_TOT + l0 + col];
    }
    for (int rep = 0; rep < 32; ++rep) {
        int idx = rep * 256 + tid;
        Wsh[idx >> 6][idx & 63] = W[idx];
    }
    const int m = tid & 127, lg = tid >> 7;
    float acc[32];
    #pragma unroll
    for (int j = 0; j < 32; ++j) acc[j] = 0.0f;
    __syncthreads();

    for (int c = 0; c < 64; ++c) {
        float w = Wsh[m][c];
        #pragma unroll
        for (int j4 = 0; j4 < 8; ++j4) {
            float4 xv = *(const float4*)&xsh[c][lg * 32 + j4 * 4];
            acc[j4 * 4 + 0] += w * xv.x;
            acc[j4 * 4 + 1] += w * xv.y;
            acc[j4 * 4 + 2] += w * xv.z;
            acc[j4 * 4 + 3] += w * xv.w;
        }
    }
    const float gb1 = ws[WS_GB1 + b * 128 + m];
    const float bm = bias[m];
    #pragma unroll
    for (int j = 0; j < 32; ++j) {
        int l = l0 + lg * 32 + j;
        xs[((size_t)b * L_TOT + l) * 128 + m] = gb1 * (acc[j] + bm);
    }
}

// One WAVE per (b, chunk). All-VALU rank-8 reduce: 4 DPP + bcast15 + bcast31
// + readlane(63). x batched 16-deep into VGPRs per y-burst. MFMA y every 16.
__global__ __launch_bounds__(64) void scan_kernel(
    const float* __restrict__ xs, const float* __restrict__ ws,
    const unsigned* __restrict__ CgP, const float* __restrict__ h0,
    float* __restrict__ out)
{
    __shared__ __align__(16) unsigned Hs[16 * 68];
    const int lane = threadIdx.x;
    const int bb = blockIdx.x >> 7, k = blockIdx.x & 127;
    const int m0 = 2 * lane;

    float Vg0[8], Vg1[8], Ug0[8], Ug1[8];
    {
        const float* vg = ws + WS_VG + (bb * 128 + m0) * 8;
        const float* ug = ws + WS_UG + (bb * 128 + m0) * 8;
        #pragma unroll
        for (int r = 0; r < 8; ++r) {
            Vg0[r] = vg[r]; Vg1[r] = vg[8 + r];
            Ug0[r] = ug[r]; Ug1[r] = ug[8 + r];
        }
    }
    const float a0 = ws[WS_A + bb * 128 + m0];
    const float a1 = ws[WS_A + bb * 128 + m0 + 1];
    float ha = h0[m0], hb = h0[m0 + 1];

    short8 Af[4][4];
    {
        const int row16 = lane & 15, grp = lane >> 4;
        #pragma unroll
        for (int ct = 0; ct < 4; ++ct)
            #pragma unroll
            for (int kc = 0; kc < 4; ++kc) {
                const unsigned* p = CgP + (bb * 64 + ct * 16 + row16) * 64 + kc * 16 + grp * 4;
                Af[ct][kc] = __builtin_bit_cast(short8, *(const uint4*)p);
            }
    }

    const float* xsp = xs + ((size_t)bb * L_TOT + (size_t)k * 512) * 128;
    float* ob[4];
    {
        int c0 = (lane >> 4) * 4;
        #pragma unroll
        for (int ct = 0; ct < 4; ++ct)
            ob[ct] = out + (size_t)(bb * 64 + ct * 16 + c0) * L_TOT + k * 512 + (lane & 15);
    }

    // prime first 16 x values
    float2 xq[16];
    #pragma unroll
    for (int i = 0; i < 16; ++i)
        xq[i] = *(const float2*)(xsp + (size_t)i * 128 + m0);

    #pragma unroll 1
    for (int t16 = 0; t16 < 32; ++t16) {
        #pragma unroll
        for (int i = 0; i < 16; ++i) {
            const float2 xv = xq[i];
            float pr[8];
            #pragma unroll
            for (int r = 0; r < 8; ++r) pr[r] = fmaf(Vg1[r], hb, Vg0[r] * ha);
            // 64-lane all-VALU sum-reduce into lane 63, per r
            #pragma unroll
            for (int r = 0; r < 8; ++r) {
                float p = pr[r];
                p = dpp_add<0xB1, 0xF, true>(p);    // xor1 (quad_perm)
                p = dpp_add<0x4E, 0xF, true>(p);    // xor2
                p = dpp_add<0x141, 0xF, true>(p);   // half-mirror -> 8-lane sums
                p = dpp_add<0x140, 0xF, true>(p);   // mirror -> 16-lane sums
                p = dpp_add<0x142, 0xa, false>(p);  // bcast15 -> 32-lane sums (rows 1,3)
                p = dpp_add<0x143, 0xc, false>(p);  // bcast31 -> 64-sum in lanes 48-63
                pr[r] = p;
            }
            float v0 = __builtin_bit_cast(float, __builtin_amdgcn_readlane(
                           __builtin_bit_cast(int, pr[0]), 63));
            float v1 = __builtin_bit_cast(float, __builtin_amdgcn_readlane(
                           __builtin_bit_cast(int, pr[1]), 63));
            float v2 = __builtin_bit_cast(float, __builtin_amdgcn_readlane(
                           __builtin_bit_cast(int, pr[2]), 63));
            float v3 = __builtin_bit_cast(float, __builtin_amdgcn_readlane(
                           __builtin_bit_cast(int, pr[3]), 63));
            float v4 = __builtin_bit_cast(float, __builtin_amdgcn_readlane(
                           __builtin_bit_cast(int, pr[4]), 63));
            float v5 = __builtin_bit_cast(float, __builtin_amdgcn_readlane(
                           __builtin_bit_cast(int, pr[5]), 63));
            float v6 = __builtin_bit_cast(float, __builtin_amdgcn_readlane(
                           __builtin_bit_cast(int, pr[6]), 63));
            float v7 = __builtin_bit_cast(float, __builtin_amdgcn_readlane(
                           __builtin_bit_cast(int, pr[7]), 63));
            // dot trees (SGPR x VGPR fmas)
            float q0 = fmaf(v1, Ug0[1], v0 * Ug0[0]);
            float q1 = fmaf(v3, Ug0[3], v2 * Ug0[2]);
            float q2 = fmaf(v5, Ug0[5], v4 * Ug0[4]);
            float q3 = fmaf(v7, Ug0[7], v6 * Ug0[6]);
            float av0 = (q0 + q1) + (q2 + q3);
            float s0 = fmaf(v1, Ug1[1], v0 * Ug1[0]);
            float s1 = fmaf(v3, Ug1[3], v2 * Ug1[2]);
            float s2 = fmaf(v5, Ug1[5], v4 * Ug1[4]);
            float s3 = fmaf(v7, Ug1[7], v6 * Ug1[6]);
            float av1 = (s0 + s1) + (s2 + s3);
            ha = fminf(10.0f, fmaxf(-10.0f, fmaf(a0, ha, av0) + xv.x));
            hb = fminf(10.0f, fmaxf(-10.0f, fmaf(a1, hb, av1) + xv.y));
            Hs[i * 68 + lane] = bf16rne(ha) | (bf16rne(hb) << 16);
        }
        // B fragments from Hs
        const int row = lane & 15, grp = lane >> 4;
        short8 Bf[4];
        #pragma unroll
        for (int kc = 0; kc < 4; ++kc)
            Bf[kc] = __builtin_bit_cast(short8,
                *(const uint4*)&Hs[row * 68 + kc * 16 + grp * 4]);
        // prefetch next 16 x values (issued BEFORE the y stores)
        {
            const int tn = (t16 + 1) & 31;
            const float* xb = xsp + (size_t)tn * 16 * 128;
            #pragma unroll
            for (int i = 0; i < 16; ++i)
                xq[i] = *(const float2*)(xb + (size_t)i * 128 + m0);
        }
        // y = clip(Cg * H16) via MFMA, store
        #pragma unroll
        for (int ct = 0; ct < 4; ++ct) {
            f32x4 acc = {0.0f, 0.0f, 0.0f, 0.0f};
            #pragma unroll
            for (int kc = 0; kc < 4; ++kc)
                acc = __builtin_amdgcn_mfma_f32_16x16x32_bf16(Af[ct][kc], Bf[kc], acc, 0, 0, 0);
            #pragma unroll
            for (int r = 0; r < 4; ++r) {
                float y = fminf(10.0f, fmaxf(-10.0f, acc[r]));
                ob[ct][(size_t)r * L_TOT + t16 * 16] = y;
            }
        }
    }
}

extern "C" void kernel_launch(void* const* d_in, const int* in_sizes, int n_in,
                              void* d_out, int out_size, void* d_ws, size_t ws_size,
                              hipStream_t stream) {
    const float* x          = (const float*)d_in[0];
    const float* g          = (const float*)d_in[1];
    const float* in_proj_w  = (const float*)d_in[2];
    const float* in_proj_b  = (const float*)d_in[3];
    const float* out_proj_w = (const float*)d_in[4];
    const float* U_base     = (const float*)d_in[5];
    const float* V_base     = (const float*)d_in[6];
    const float* a_base     = (const float*)d_in[7];
    const float* mod_uv_w   = (const float*)d_in[8];
    const float* mod_uv_b   = (const float*)d_in[9];
    const float* mod_a_w    = (const float*)d_in[10];
    const float* mod_a_b    = (const float*)d_in[11];
    const float* mod_B_w    = (const float*)d_in[12];
    const float* mod_B_b    = (const float*)d_in[13];
    const float* mod_C_w    = (const float*)d_in[14];
    const float* mod_C_b    = (const float*)d_in[15];
    const float* h0         = (const float*)d_in[16];
    float* out = (float*)d_out;
    float* ws  = (float*)d_ws;

    hipLaunchKernelGGL(mod_kernel, dim3(4), dim3(128), 0, stream,
                       g, U_base, V_base, a_base, out_proj_w,
                       mod_uv_w, mod_uv_b, mod_a_w, mod_a_b,
                       mod_B_w, mod_B_b, mod_C_w, mod_C_b, ws);
    hipLaunchKernelGGL(inproj_kernel, dim3(1024, 4), dim3(256), 0, stream,
                       x, in_proj_w, in_proj_b, ws, ws + WS_XS);
    hipLaunchKernelGGL(scan_kernel, dim3(512), dim3(64), 0, stream,
                       ws + WS_XS, ws, (const unsigned*)(ws + WS_CGP), h0, out);
}

// Round 5
// 297.284 us; speedup vs baseline: 2.2554x; 1.0024x over previous
//
#include <hip/hip_runtime.h>

#define L_TOT 65536

// ws float offsets
#define WS_UG   0        // [4][128][8]
#define WS_VG   4096     // [4][128][8]
#define WS_A    8192     // [4][128]
#define WS_GB1  8704     // [4][128]
#define WS_CGP  32768    // uint[4][64][64]: packed bf16 pairs of Cg
#define WS_XS   65536    // [4][65536][128] fp32 x_seq

typedef __attribute__((ext_vector_type(8))) short short8;
typedef __attribute__((ext_vector_type(4))) float f32x4;

__device__ __forceinline__ unsigned bf16rne(float f) {
    unsigned u = __builtin_bit_cast(unsigned, f);
    return (u + 0x7fffu + ((u >> 16) & 1u)) >> 16;
}

// v += dpp_perm(v); all-VALU. ctrl/row_mask must be compile-time constants.
template <int CTRL, int ROW_MASK, bool BOUND>
__device__ __forceinline__ float dpp_add(float v) {
    int t = __builtin_amdgcn_update_dpp(0, __builtin_bit_cast(int, v),
                                        CTRL, ROW_MASK, 0xF, BOUND);
    return v + __builtin_bit_cast(float, t);
}

__global__ __launch_bounds__(128) void mod_kernel(
    const float* __restrict__ g,
    const float* __restrict__ U_base, const float* __restrict__ V_base,
    const float* __restrict__ a_base, const float* __restrict__ out_proj_w,
    const float* __restrict__ mod_uv_w, const float* __restrict__ mod_uv_b,
    const float* __restrict__ mod_a_w, const float* __restrict__ mod_a_b,
    const float* __restrict__ mod_B_w, const float* __restrict__ mod_B_b,
    const float* __restrict__ mod_C_w, const float* __restrict__ mod_C_b,
    float* __restrict__ ws)
{
    __shared__ float gsh[64];
    __shared__ float uvs[16];
    __shared__ float gCs[64];
    const int b = blockIdx.x, tid = threadIdx.x;
    if (tid < 64) gsh[tid] = g[b * 64 + tid];
    __syncthreads();
    if (tid < 16) {
        float s = mod_uv_b[tid];
        for (int d = 0; d < 64; ++d) s += mod_uv_w[tid * 64 + d] * gsh[d];
        uvs[tid] = fminf(0.5f, fmaxf(-0.5f, s));
    }
    float ga_v, gB_v;
    {
        float s = mod_a_b[tid];
        for (int d = 0; d < 64; ++d) s += mod_a_w[tid * 64 + d] * gsh[d];
        ga_v = fminf(2.0f, fmaxf(-2.0f, s));
    }
    {
        float s = mod_B_b[tid];
        for (int d = 0; d < 64; ++d) s += mod_B_w[tid * 64 + d] * gsh[d];
        gB_v = 1.0f + fminf(1.0f, fmaxf(-1.0f, s));
    }
    if (tid < 64) {
        float s = mod_C_b[tid];
        for (int d = 0; d < 64; ++d) s += mod_C_w[tid * 64 + d] * gsh[d];
        gCs[tid] = 1.0f + fminf(0.5f, fmaxf(-0.5f, s));
    }
    __syncthreads();
    for (int idx = tid; idx < 1024; idx += 128) {
        int m = idx >> 3, r = idx & 7;
        ws[WS_UG + (b * 128 + m) * 8 + r] = U_base[m * 8 + r] * (1.0f + uvs[r]);
        ws[WS_VG + (b * 128 + m) * 8 + r] = V_base[m * 8 + r] * (1.0f + uvs[8 + r]);
    }
    ws[WS_A   + b * 128 + tid] = a_base[tid] + ga_v;
    ws[WS_GB1 + b * 128 + tid] = gB_v;
    unsigned* CgP = (unsigned*)(ws + WS_CGP);
    for (int idx = tid; idx < 4096; idx += 128) {
        int c = idx >> 6, j = idx & 63;
        float s = gCs[c];
        float c0 = out_proj_w[c * 128 + 2 * j]     * s;
        float c1 = out_proj_w[c * 128 + 2 * j + 1] * s;
        CgP[(b * 64 + c) * 64 + j] = bf16rne(c0) | (bf16rne(c1) << 16);
    }
}

__global__ __launch_bounds__(256) void inproj_kernel(
    const float* __restrict__ x, const float* __restrict__ W,
    const float* __restrict__ bias, const float* __restrict__ ws,
    float* __restrict__ xs)
{
    __shared__ float xsh[64][68];
    __shared__ float Wsh[128][65];
    const int tid = threadIdx.x;
    const int b = blockIdx.y;
    const int l0 = blockIdx.x * 64;

    for (int rep = 0; rep < 16; ++rep) {
        int idx = rep * 256 + tid;
        int c = idx >> 6, col = idx & 63;
        xsh[c][col] = x[((size_t)(b * 64 + c)) * L_TOT + l0 + col];
    }
    for (int rep = 0; rep < 32; ++rep) {
        int idx = rep * 256 + tid;
        Wsh[idx >> 6][idx & 63] = W[idx];
    }
    const int m = tid & 127, lg = tid >> 7;
    float acc[32];
    #pragma unroll
    for (int j = 0; j < 32; ++j) acc[j] = 0.0f;
    __syncthreads();

    for (int c = 0; c < 64; ++c) {
        float w = Wsh[m][c];
        #pragma unroll
        for (int j4 = 0; j4 < 8; ++j4) {
            float4 xv = *(const float4*)&xsh[c][lg * 32 + j4 * 4];
            acc[j4 * 4 + 0] += w * xv.x;
            acc[j4 * 4 + 1] += w * xv.y;
            acc[j4 * 4 + 2] += w * xv.z;
            acc[j4 * 4 + 3] += w * xv.w;
        }
    }
    const float gb1 = ws[WS_GB1 + b * 128 + m];
    const float bm = bias[m];
    #pragma unroll
    for (int j = 0; j < 32; ++j) {
        int l = l0 + lg * 32 + j;
        xs[((size_t)b * L_TOT + l) * 128 + m] = gb1 * (acc[j] + bm);
    }
}

// One WAVE per (b, chunk). All-VALU rank-8 reduce: 4 DPP + bcast15 + bcast31
// + readlane(63). x batched 16-deep into VGPRs per y-burst. MFMA y every 16.
// __launch_bounds__(64, 1): 1 wave/SIMD -> full register budget, NO SPILLS
// (round-4's VGPR_Count=100 forced scratch spills of Af/xq -> ~700 stall
// cycles/step).
__global__ __launch_bounds__(64, 1) void scan_kernel(
    const float* __restrict__ xs, const float* __restrict__ ws,
    const unsigned* __restrict__ CgP, const float* __restrict__ h0,
    float* __restrict__ out)
{
    __shared__ __align__(16) unsigned Hs[16 * 68];
    const int lane = threadIdx.x;
    const int bb = blockIdx.x >> 7, k = blockIdx.x & 127;
    const int m0 = 2 * lane;

    float Vg0[8], Vg1[8], Ug0[8], Ug1[8];
    {
        const float* vg = ws + WS_VG + (bb * 128 + m0) * 8;
        const float* ug = ws + WS_UG + (bb * 128 + m0) * 8;
        #pragma unroll
        for (int r = 0; r < 8; ++r) {
            Vg0[r] = vg[r]; Vg1[r] = vg[8 + r];
            Ug0[r] = ug[r]; Ug1[r] = ug[8 + r];
        }
    }
    const float a0 = ws[WS_A + bb * 128 + m0];
    const float a1 = ws[WS_A + bb * 128 + m0 + 1];
    float ha = h0[m0], hb = h0[m0 + 1];

    short8 Af[4][4];
    {
        const int row16 = lane & 15, grp = lane >> 4;
        #pragma unroll
        for (int ct = 0; ct < 4; ++ct)
            #pragma unroll
            for (int kc = 0; kc < 4; ++kc) {
                const unsigned* p = CgP + (bb * 64 + ct * 16 + row16) * 64 + kc * 16 + grp * 4;
                Af[ct][kc] = __builtin_bit_cast(short8, *(const uint4*)p);
            }
    }

    const float* xsp = xs + ((size_t)bb * L_TOT + (size_t)k * 512) * 128;
    float* ob[4];
    {
        int c0 = (lane >> 4) * 4;
        #pragma unroll
        for (int ct = 0; ct < 4; ++ct)
            ob[ct] = out + (size_t)(bb * 64 + ct * 16 + c0) * L_TOT + k * 512 + (lane & 15);
    }

    // prime first 16 x values
    float2 xq[16];
    #pragma unroll
    for (int i = 0; i < 16; ++i)
        xq[i] = *(const float2*)(xsp + (size_t)i * 128 + m0);

    #pragma unroll 1
    for (int t16 = 0; t16 < 32; ++t16) {
        #pragma unroll
        for (int i = 0; i < 16; ++i) {
            const float2 xv = xq[i];
            float pr[8];
            #pragma unroll
            for (int r = 0; r < 8; ++r) pr[r] = fmaf(Vg1[r], hb, Vg0[r] * ha);
            // 64-lane all-VALU sum-reduce into lane 63, per r
            #pragma unroll
            for (int r = 0; r < 8; ++r) {
                float p = pr[r];
                p = dpp_add<0xB1, 0xF, true>(p);    // xor1 (quad_perm)
                p = dpp_add<0x4E, 0xF, true>(p);    // xor2
                p = dpp_add<0x141, 0xF, true>(p);   // half-mirror -> 8-lane sums
                p = dpp_add<0x140, 0xF, true>(p);   // mirror -> 16-lane sums
                p = dpp_add<0x142, 0xa, false>(p);  // bcast15 -> 32-lane sums (rows 1,3)
                p = dpp_add<0x143, 0xc, false>(p);  // bcast31 -> 64-sum in lanes 48-63
                pr[r] = p;
            }
            float v0 = __builtin_bit_cast(float, __builtin_amdgcn_readlane(
                           __builtin_bit_cast(int, pr[0]), 63));
            float v1 = __builtin_bit_cast(float, __builtin_amdgcn_readlane(
                           __builtin_bit_cast(int, pr[1]), 63));
            float v2 = __builtin_bit_cast(float, __builtin_amdgcn_readlane(
                           __builtin_bit_cast(int, pr[2]), 63));
            float v3 = __builtin_bit_cast(float, __builtin_amdgcn_readlane(
                           __builtin_bit_cast(int, pr[3]), 63));
            float v4 = __builtin_bit_cast(float, __builtin_amdgcn_readlane(
                           __builtin_bit_cast(int, pr[4]), 63));
            float v5 = __builtin_bit_cast(float, __builtin_amdgcn_readlane(
                           __builtin_bit_cast(int, pr[5]), 63));
            float v6 = __builtin_bit_cast(float, __builtin_amdgcn_readlane(
                           __builtin_bit_cast(int, pr[6]), 63));
            float v7 = __builtin_bit_cast(float, __builtin_amdgcn_readlane(
                           __builtin_bit_cast(int, pr[7]), 63));
            // dot trees (SGPR x VGPR fmas)
            float q0 = fmaf(v1, Ug0[1], v0 * Ug0[0]);
            float q1 = fmaf(v3, Ug0[3], v2 * Ug0[2]);
            float q2 = fmaf(v5, Ug0[5], v4 * Ug0[4]);
            float q3 = fmaf(v7, Ug0[7], v6 * Ug0[6]);
            float av0 = (q0 + q1) + (q2 + q3);
            float s0 = fmaf(v1, Ug1[1], v0 * Ug1[0]);
            float s1 = fmaf(v3, Ug1[3], v2 * Ug1[2]);
            float s2 = fmaf(v5, Ug1[5], v4 * Ug1[4]);
            float s3 = fmaf(v7, Ug1[7], v6 * Ug1[6]);
            float av1 = (s0 + s1) + (s2 + s3);
            ha = fminf(10.0f, fmaxf(-10.0f, fmaf(a0, ha, av0) + xv.x));
            hb = fminf(10.0f, fmaxf(-10.0f, fmaf(a1, hb, av1) + xv.y));
            Hs[i * 68 + lane] = bf16rne(ha) | (bf16rne(hb) << 16);
        }
        // B fragments from Hs
        const int row = lane & 15, grp = lane >> 4;
        short8 Bf[4];
        #pragma unroll
        for (int kc = 0; kc < 4; ++kc)
            Bf[kc] = __builtin_bit_cast(short8,
                *(const uint4*)&Hs[row * 68 + kc * 16 + grp * 4]);
        // prefetch next 16 x values (issued BEFORE the y stores)
        {
            const int tn = (t16 + 1) & 31;
            const float* xb = xsp + (size_t)tn * 16 * 128;
            #pragma unroll
            for (int i = 0; i < 16; ++i)
                xq[i] = *(const float2*)(xb + (size_t)i * 128 + m0);
        }
        // y = clip(Cg * H16) via MFMA, store
        #pragma unroll
        for (int ct = 0; ct < 4; ++ct) {
            f32x4 acc = {0.0f, 0.0f, 0.0f, 0.0f};
            #pragma unroll
            for (int kc = 0; kc < 4; ++kc)
                acc = __builtin_amdgcn_mfma_f32_16x16x32_bf16(Af[ct][kc], Bf[kc], acc, 0, 0, 0);
            #pragma unroll
            for (int r = 0; r < 4; ++r) {
                float y = fminf(10.0f, fmaxf(-10.0f, acc[r]));
                ob[ct][(size_t)r * L_TOT + t16 * 16] = y;
            }
        }
    }
}

extern "C" void kernel_launch(void* const* d_in, const int* in_sizes, int n_in,
                              void* d_out, int out_size, void* d_ws, size_t ws_size,
                              hipStream_t stream) {
    const float* x          = (const float*)d_in[0];
    const float* g          = (const float*)d_in[1];
    const float* in_proj_w  = (const float*)d_in[2];
    const float* in_proj_b  = (const float*)d_in[3];
    const float* out_proj_w = (const float*)d_in[4];
    const float* U_base     = (const float*)d_in[5];
    const float* V_base     = (const float*)d_in[6];
    const float* a_base     = (const float*)d_in[7];
    const float* mod_uv_w   = (const float*)d_in[8];
    const float* mod_uv_b   = (const float*)d_in[9];
    const float* mod_a_w    = (const float*)d_in[10];
    const float* mod_a_b    = (const float*)d_in[11];
    const float* mod_B_w    = (const float*)d_in[12];
    const float* mod_B_b    = (const float*)d_in[13];
    const float* mod_C_w    = (const float*)d_in[14];
    const float* mod_C_b    = (const float*)d_in[15];
    const float* h0         = (const float*)d_in[16];
    float* out = (float*)d_out;
    float* ws  = (float*)d_ws;

    hipLaunchKernelGGL(mod_kernel, dim3(4), dim3(128), 0, stream,
                       g, U_base, V_base, a_base, out_proj_w,
                       mod_uv_w, mod_uv_b, mod_a_w, mod_a_b,
                       mod_B_w, mod_B_b, mod_C_w, mod_C_b, ws);
    hipLaunchKernelGGL(inproj_kernel, dim3(1024, 4), dim3(256), 0, stream,
                       x, in_proj_w, in_proj_b, ws, ws + WS_XS);
    hipLaunchKernelGGL(scan_kernel, dim3(512), dim3(64), 0, stream,
                       ws + WS_XS, ws, (const unsigned*)(ws + WS_CGP), h0, out);
}

// Round 6
// 218.223 us; speedup vs baseline: 3.0725x; 1.3623x over previous
//
#include <hip/hip_runtime.h>

#define L_TOT 65536

// ws float offsets
#define WS_UG   0        // [4][128][8]
#define WS_VG   4096     // [4][128][8]
#define WS_A    8192     // [4][128]
#define WS_GB1  8704     // [4][128]
#define WS_CGP  32768    // uint[4][64][64]: packed bf16 pairs of Cg
#define WS_XS   65536    // [4][65536][128] fp32 x_seq

typedef __attribute__((ext_vector_type(8))) short short8;
typedef __attribute__((ext_vector_type(4))) float f32x4;

__device__ __forceinline__ unsigned bf16rne(float f) {
    unsigned u = __builtin_bit_cast(unsigned, f);
    return (u + 0x7fffu + ((u >> 16) & 1u)) >> 16;
}

// One fused v_add_f32_dpp per lane-exchange level, 8 independent chains
// interleaved (dependent ops 8 apart -> DPP hazard-safe).
#define DPP_ROW(CT) \
    "v_add_f32_dpp %0, %0, %0 " CT "\n\t" \
    "v_add_f32_dpp %1, %1, %1 " CT "\n\t" \
    "v_add_f32_dpp %2, %2, %2 " CT "\n\t" \
    "v_add_f32_dpp %3, %3, %3 " CT "\n\t" \
    "v_add_f32_dpp %4, %4, %4 " CT "\n\t" \
    "v_add_f32_dpp %5, %5, %5 " CT "\n\t" \
    "v_add_f32_dpp %6, %6, %6 " CT "\n\t" \
    "v_add_f32_dpp %7, %7, %7 " CT "\n\t"

__global__ __launch_bounds__(128) void mod_kernel(
    const float* __restrict__ g,
    const float* __restrict__ U_base, const float* __restrict__ V_base,
    const float* __restrict__ a_base, const float* __restrict__ out_proj_w,
    const float* __restrict__ mod_uv_w, const float* __restrict__ mod_uv_b,
    const float* __restrict__ mod_a_w, const float* __restrict__ mod_a_b,
    const float* __restrict__ mod_B_w, const float* __restrict__ mod_B_b,
    const float* __restrict__ mod_C_w, const float* __restrict__ mod_C_b,
    float* __restrict__ ws)
{
    __shared__ float gsh[64];
    __shared__ float uvs[16];
    __shared__ float gCs[64];
    const int b = blockIdx.x, tid = threadIdx.x;
    if (tid < 64) gsh[tid] = g[b * 64 + tid];
    __syncthreads();
    if (tid < 16) {
        float s = mod_uv_b[tid];
        for (int d = 0; d < 64; ++d) s += mod_uv_w[tid * 64 + d] * gsh[d];
        uvs[tid] = fminf(0.5f, fmaxf(-0.5f, s));
    }
    float ga_v, gB_v;
    {
        float s = mod_a_b[tid];
        for (int d = 0; d < 64; ++d) s += mod_a_w[tid * 64 + d] * gsh[d];
        ga_v = fminf(2.0f, fmaxf(-2.0f, s));
    }
    {
        float s = mod_B_b[tid];
        for (int d = 0; d < 64; ++d) s += mod_B_w[tid * 64 + d] * gsh[d];
        gB_v = 1.0f + fminf(1.0f, fmaxf(-1.0f, s));
    }
    if (tid < 64) {
        float s = mod_C_b[tid];
        for (int d = 0; d < 64; ++d) s += mod_C_w[tid * 64 + d] * gsh[d];
        gCs[tid] = 1.0f + fminf(0.5f, fmaxf(-0.5f, s));
    }
    __syncthreads();
    for (int idx = tid; idx < 1024; idx += 128) {
        int m = idx >> 3, r = idx & 7;
        ws[WS_UG + (b * 128 + m) * 8 + r] = U_base[m * 8 + r] * (1.0f + uvs[r]);
        ws[WS_VG + (b * 128 + m) * 8 + r] = V_base[m * 8 + r] * (1.0f + uvs[8 + r]);
    }
    ws[WS_A   + b * 128 + tid] = a_base[tid] + ga_v;
    ws[WS_GB1 + b * 128 + tid] = gB_v;
    unsigned* CgP = (unsigned*)(ws + WS_CGP);
    for (int idx = tid; idx < 4096; idx += 128) {
        int c = idx >> 6, j = idx & 63;
        float s = gCs[c];
        float c0 = out_proj_w[c * 128 + 2 * j]     * s;
        float c1 = out_proj_w[c * 128 + 2 * j + 1] * s;
        CgP[(b * 64 + c) * 64 + j] = bf16rne(c0) | (bf16rne(c1) << 16);
    }
}

__global__ __launch_bounds__(256) void inproj_kernel(
    const float* __restrict__ x, const float* __restrict__ W,
    const float* __restrict__ bias, const float* __restrict__ ws,
    float* __restrict__ xs)
{
    __shared__ float xsh[64][68];
    __shared__ float Wsh[128][65];
    const int tid = threadIdx.x;
    const int b = blockIdx.y;
    const int l0 = blockIdx.x * 64;

    for (int rep = 0; rep < 16; ++rep) {
        int idx = rep * 256 + tid;
        int c = idx >> 6, col = idx & 63;
        xsh[c][col] = x[((size_t)(b * 64 + c)) * L_TOT + l0 + col];
    }
    for (int rep = 0; rep < 32; ++rep) {
        int idx = rep * 256 + tid;
        Wsh[idx >> 6][idx & 63] = W[idx];
    }
    const int m = tid & 127, lg = tid >> 7;
    float acc[32];
    #pragma unroll
    for (int j = 0; j < 32; ++j) acc[j] = 0.0f;
    __syncthreads();

    for (int c = 0; c < 64; ++c) {
        float w = Wsh[m][c];
        #pragma unroll
        for (int j4 = 0; j4 < 8; ++j4) {
            float4 xv = *(const float4*)&xsh[c][lg * 32 + j4 * 4];
            acc[j4 * 4 + 0] += w * xv.x;
            acc[j4 * 4 + 1] += w * xv.y;
            acc[j4 * 4 + 2] += w * xv.z;
            acc[j4 * 4 + 3] += w * xv.w;
        }
    }
    const float gb1 = ws[WS_GB1 + b * 128 + m];
    const float bm = bias[m];
    #pragma unroll
    for (int j = 0; j < 32; ++j) {
        int l = l0 + lg * 32 + j;
        xs[((size_t)b * L_TOT + l) * 128 + m] = gb1 * (acc[j] + bm);
    }
}

// One WAVE per (b, chunk). Rank-8 all-reduce as 48 fused v_add_f32_dpp
// (inline asm; round-5 PMC showed builtin update_dpp compiled to a 3-instr
// mov/mov_dpp/add triple -> ~280 VALU/step issue-bound). MFMA y every 16.
__global__ __launch_bounds__(64, 1) void scan_kernel(
    const float* __restrict__ xs, const float* __restrict__ ws,
    const unsigned* __restrict__ CgP, const float* __restrict__ h0,
    float* __restrict__ out)
{
    __shared__ __align__(16) unsigned Hs[16 * 68];
    const int lane = threadIdx.x;
    const int bb = blockIdx.x >> 7, k = blockIdx.x & 127;
    const int m0 = 2 * lane;

    float Vg0[8], Vg1[8], Ug0[8], Ug1[8];
    {
        const float* vg = ws + WS_VG + (bb * 128 + m0) * 8;
        const float* ug = ws + WS_UG + (bb * 128 + m0) * 8;
        #pragma unroll
        for (int r = 0; r < 8; ++r) {
            Vg0[r] = vg[r]; Vg1[r] = vg[8 + r];
            Ug0[r] = ug[r]; Ug1[r] = ug[8 + r];
        }
    }
    const float a0 = ws[WS_A + bb * 128 + m0];
    const float a1 = ws[WS_A + bb * 128 + m0 + 1];
    float ha = h0[m0], hb = h0[m0 + 1];

    short8 Af[4][4];
    {
        const int row16 = lane & 15, grp = lane >> 4;
        #pragma unroll
        for (int ct = 0; ct < 4; ++ct)
            #pragma unroll
            for (int kc = 0; kc < 4; ++kc) {
                const unsigned* p = CgP + (bb * 64 + ct * 16 + row16) * 64 + kc * 16 + grp * 4;
                Af[ct][kc] = __builtin_bit_cast(short8, *(const uint4*)p);
            }
    }

    const float* xsp = xs + ((size_t)bb * L_TOT + (size_t)k * 512) * 128;
    float* ob[4];
    {
        int c0 = (lane >> 4) * 4;
        #pragma unroll
        for (int ct = 0; ct < 4; ++ct)
            ob[ct] = out + (size_t)(bb * 64 + ct * 16 + c0) * L_TOT + k * 512 + (lane & 15);
    }

    // prime first 16 x values
    float2 xq[16];
    #pragma unroll
    for (int i = 0; i < 16; ++i)
        xq[i] = *(const float2*)(xsp + (size_t)i * 128 + m0);

    #pragma unroll 1
    for (int t16 = 0; t16 < 32; ++t16) {
        #pragma unroll
        for (int i = 0; i < 16; ++i) {
            const float2 xv = xq[i];
            float p0 = fmaf(Vg1[0], hb, Vg0[0] * ha);
            float p1 = fmaf(Vg1[1], hb, Vg0[1] * ha);
            float p2 = fmaf(Vg1[2], hb, Vg0[2] * ha);
            float p3 = fmaf(Vg1[3], hb, Vg0[3] * ha);
            float p4 = fmaf(Vg1[4], hb, Vg0[4] * ha);
            float p5 = fmaf(Vg1[5], hb, Vg0[5] * ha);
            float p6 = fmaf(Vg1[6], hb, Vg0[6] * ha);
            float p7 = fmaf(Vg1[7], hb, Vg0[7] * ha);
            // 64-lane all-VALU sum-reduce into lanes 48-63 (full sum), 48 DPP adds
            asm volatile(
                "s_nop 1\n\t"
                DPP_ROW("quad_perm:[1,0,3,2] row_mask:0xf bank_mask:0xf bound_ctrl:1")
                DPP_ROW("quad_perm:[2,3,0,1] row_mask:0xf bank_mask:0xf bound_ctrl:1")
                DPP_ROW("row_half_mirror row_mask:0xf bank_mask:0xf bound_ctrl:1")
                DPP_ROW("row_mirror row_mask:0xf bank_mask:0xf bound_ctrl:1")
                DPP_ROW("row_bcast:15 row_mask:0xa bank_mask:0xf")
                DPP_ROW("row_bcast:31 row_mask:0xc bank_mask:0xf")
                : "+v"(p0), "+v"(p1), "+v"(p2), "+v"(p3),
                  "+v"(p4), "+v"(p5), "+v"(p6), "+v"(p7));
            float v0 = __builtin_bit_cast(float, __builtin_amdgcn_readlane(
                           __builtin_bit_cast(int, p0), 63));
            float v1 = __builtin_bit_cast(float, __builtin_amdgcn_readlane(
                           __builtin_bit_cast(int, p1), 63));
            float v2 = __builtin_bit_cast(float, __builtin_amdgcn_readlane(
                           __builtin_bit_cast(int, p2), 63));
            float v3 = __builtin_bit_cast(float, __builtin_amdgcn_readlane(
                           __builtin_bit_cast(int, p3), 63));
            float v4 = __builtin_bit_cast(float, __builtin_amdgcn_readlane(
                           __builtin_bit_cast(int, p4), 63));
            float v5 = __builtin_bit_cast(float, __builtin_amdgcn_readlane(
                           __builtin_bit_cast(int, p5), 63));
            float v6 = __builtin_bit_cast(float, __builtin_amdgcn_readlane(
                           __builtin_bit_cast(int, p6), 63));
            float v7 = __builtin_bit_cast(float, __builtin_amdgcn_readlane(
                           __builtin_bit_cast(int, p7), 63));
            // dot trees (SGPR x VGPR fmas)
            float q0 = fmaf(v1, Ug0[1], v0 * Ug0[0]);
            float q1 = fmaf(v3, Ug0[3], v2 * Ug0[2]);
            float q2 = fmaf(v5, Ug0[5], v4 * Ug0[4]);
            float q3 = fmaf(v7, Ug0[7], v6 * Ug0[6]);
            float av0 = (q0 + q1) + (q2 + q3);
            float s0 = fmaf(v1, Ug1[1], v0 * Ug1[0]);
            float s1 = fmaf(v3, Ug1[3], v2 * Ug1[2]);
            float s2 = fmaf(v5, Ug1[5], v4 * Ug1[4]);
            float s3 = fmaf(v7, Ug1[7], v6 * Ug1[6]);
            float av1 = (s0 + s1) + (s2 + s3);
            ha = fminf(10.0f, fmaxf(-10.0f, fmaf(a0, ha, av0) + xv.x));
            hb = fminf(10.0f, fmaxf(-10.0f, fmaf(a1, hb, av1) + xv.y));
            Hs[i * 68 + lane] = bf16rne(ha) | (bf16rne(hb) << 16);
        }
        // B fragments from Hs
        const int row = lane & 15, grp = lane >> 4;
        short8 Bf[4];
        #pragma unroll
        for (int kc = 0; kc < 4; ++kc)
            Bf[kc] = __builtin_bit_cast(short8,
                *(const uint4*)&Hs[row * 68 + kc * 16 + grp * 4]);
        // prefetch next 16 x values (issued BEFORE the y stores)
        {
            const int tn = (t16 + 1) & 31;
            const float* xb = xsp + (size_t)tn * 16 * 128;
            #pragma unroll
            for (int i = 0; i < 16; ++i)
                xq[i] = *(const float2*)(xb + (size_t)i * 128 + m0);
        }
        // y = clip(Cg * H16) via MFMA, store
        #pragma unroll
        for (int ct = 0; ct < 4; ++ct) {
            f32x4 acc = {0.0f, 0.0f, 0.0f, 0.0f};
            #pragma unroll
            for (int kc = 0; kc < 4; ++kc)
                acc = __builtin_amdgcn_mfma_f32_16x16x32_bf16(Af[ct][kc], Bf[kc], acc, 0, 0, 0);
            #pragma unroll
            for (int r = 0; r < 4; ++r) {
                float y = fminf(10.0f, fmaxf(-10.0f, acc[r]));
                ob[ct][(size_t)r * L_TOT + t16 * 16] = y;
            }
        }
    }
}

extern "C" void kernel_launch(void* const* d_in, const int* in_sizes, int n_in,
                              void* d_out, int out_size, void* d_ws, size_t ws_size,
                              hipStream_t stream) {
    const float* x          = (const float*)d_in[0];
    const float* g          = (const float*)d_in[1];
    const float* in_proj_w  = (const float*)d_in[2];
    const float* in_proj_b  = (const float*)d_in[3];
    const float* out_proj_w = (const float*)d_in[4];
    const float* U_base     = (const float*)d_in[5];
    const float* V_base     = (const float*)d_in[6];
    const float* a_base     = (const float*)d_in[7];
    const float* mod_uv_w   = (const float*)d_in[8];
    const float* mod_uv_b   = (const float*)d_in[9];
    const float* mod_a_w    = (const float*)d_in[10];
    const float* mod_a_b    = (const float*)d_in[11];
    const float* mod_B_w    = (const float*)d_in[12];
    const float* mod_B_b    = (const float*)d_in[13];
    const float* mod_C_w    = (const float*)d_in[14];
    const float* mod_C_b    = (const float*)d_in[15];
    const float* h0         = (const float*)d_in[16];
    float* out = (float*)d_out;
    float* ws  = (float*)d_ws;

    hipLaunchKernelGGL(mod_kernel, dim3(4), dim3(128), 0, stream,
                       g, U_base, V_base, a_base, out_proj_w,
                       mod_uv_w, mod_uv_b, mod_a_w, mod_a_b,
                       mod_B_w, mod_B_b, mod_C_w, mod_C_b, ws);
    hipLaunchKernelGGL(inproj_kernel, dim3(1024, 4), dim3(256), 0, stream,
                       x, in_proj_w, in_proj_b, ws, ws + WS_XS);
    hipLaunchKernelGGL(scan_kernel, dim3(512), dim3(64), 0, stream,
                       ws + WS_XS, ws, (const unsigned*)(ws + WS_CGP), h0, out);
}